// Round 14
// baseline (5768.119 us; speedup 1.0000x reference)
//
#include <hip/hip_runtime.h>

typedef unsigned short u16;
typedef unsigned int u32;
typedef unsigned long long u64;
typedef float f32x4 __attribute__((ext_vector_type(4)));
typedef __bf16 bf16x8 __attribute__((ext_vector_type(8)));
typedef u16 u16x8 __attribute__((ext_vector_type(8)));
typedef u32 u32x4 __attribute__((ext_vector_type(4)));

#define T_STEPS 512
#define BATCH 64
#define HDIM 1024
#define GDIM 4096            // 4*H
#define HS_ELEMS (33554432u) // 512*64*1024
#define XP_STEP 262144       // u16 per t: 64 blk * 4 gate * 1024

__device__ __forceinline__ u16 f2bf(float f) {
  union { float f; u32 u; } v; v.f = f;
  u32 r = v.u + 0x7fffu + ((v.u >> 16) & 1u);
  return (u16)(r >> 16);
}
__device__ __forceinline__ float bf2f(u16 b) {
  union { u32 u; float f; } v; v.u = ((u32)b) << 16;
  return v.f;
}
__device__ __forceinline__ float sigm(float x) { return 1.f / (1.f + __expf(-x)); }
__device__ __forceinline__ float tanh_fast(float x) { return 1.f - 2.f / (__expf(2.f * x) + 1.f); }

// async global->LDS, 16B per lane
__device__ __forceinline__ void gload16(const void* g, void* l) {
  __builtin_amdgcn_global_load_lds(
      (const __attribute__((address_space(1))) u32*)g,
      (__attribute__((address_space(3))) u32*)l, 16, 0, 0);
}
// LLC-coherent 16B load (bypass L1+L2; agent scope)
__device__ __forceinline__ u32x4 cload16(const void* g) {
  u32x4 r;
  asm volatile("global_load_dwordx4 %0, %1, off sc0 sc1" : "=&v"(r) : "v"(g) : "memory");
  return r;
}

// ---------------------------------------------------------------------------
// Kernel 1: transpose+convert W_x, W_h: [1024][4096] fp32 -> [4096][1024] bf16.
// ---------------------------------------------------------------------------
__global__ void transpose_w(const float* __restrict__ Wx, const float* __restrict__ Wh,
                            u16* __restrict__ WxT, u16* __restrict__ WhT) {
  __shared__ float tile[32][33];
  const float* src = blockIdx.z ? Wh : Wx;
  u16* dst = blockIdx.z ? WhT : WxT;
  const int n0 = blockIdx.x * 32, k0 = blockIdx.y * 32;
  const int tx = threadIdx.x, ty = threadIdx.y;
#pragma unroll
  for (int i = 0; i < 4; ++i)
    tile[ty + i * 8][tx] = src[(size_t)(k0 + ty + i * 8) * GDIM + n0 + tx];
  __syncthreads();
#pragma unroll
  for (int i = 0; i < 4; ++i)
    dst[(size_t)(n0 + ty + i * 8) * HDIM + k0 + tx] = f2bf(tile[tx][ty + i * 8]);
}

// ---------------------------------------------------------------------------
// Kernel 1b: convert X fp32 -> bf16 into d_out scratch (dead after gemm).
// ---------------------------------------------------------------------------
__global__ void convert_x(const float* __restrict__ X, u16* __restrict__ Xbf) {
  const size_t i = ((size_t)blockIdx.x * 256 + threadIdx.x) * 8;
  const float4 a = *(const float4*)&X[i];
  const float4 b = *(const float4*)&X[i + 4];
  u16x8 o;
  o[0] = f2bf(a.x); o[1] = f2bf(a.y); o[2] = f2bf(a.z); o[3] = f2bf(a.w);
  o[4] = f2bf(b.x); o[5] = f2bf(b.y); o[6] = f2bf(b.z); o[7] = f2bf(b.w);
  *(u16x8*)&Xbf[i] = o;
}

// ---------------------------------------------------------------------------
// Kernel 2: Xp = bf16(Xbf @ W_x + b), m97-style (R9-proven ~300us).
// Epilogue blocked for the 64-block recurrence:
//   Xp[t][blk=bg*16+cr][gate][b_el*64+hcol]; bg=b>>4, b_el=b&15, cr=col>>6.
// ---------------------------------------------------------------------------
__global__ __launch_bounds__(256) void gemm_xp(
    const u16* __restrict__ Xbf, const u16* __restrict__ WxT,
    const float* __restrict__ bias, u16* __restrict__ Xp) {
  __shared__ u16 As[128 * 32];
  __shared__ u16 Bs[128 * 32];
  const int tid = threadIdx.x;
  const int lane = tid & 63, w = tid >> 6;
  const int rl = lane & 15, gq = lane >> 4, g8 = gq * 8;
  const int swz = (blockIdx.x & 7) * 1024 + (blockIdx.x >> 3);
  const int m0 = (swz >> 5) * 128, n0 = (swz & 31) * 128;
  const int rbase = (w >> 1) * 64, cbase = (w & 1) * 64;
  const int r0 = tid >> 2, c0 = (tid & 3) * 8;

  f32x4 acc[4][4] = {};
  for (int k0 = 0; k0 < 1024; k0 += 32) {
    gload16(&Xbf[(size_t)(m0 + r0) * 1024 + k0 + c0], &As[w * 512]);
    gload16(&Xbf[(size_t)(m0 + r0 + 64) * 1024 + k0 + c0], &As[2048 + w * 512]);
    gload16(&WxT[(size_t)(n0 + r0) * 1024 + k0 + c0], &Bs[w * 512]);
    gload16(&WxT[(size_t)(n0 + r0 + 64) * 1024 + k0 + c0], &Bs[2048 + w * 512]);
    __syncthreads();
    bf16x8 av[4], bv[4];
#pragma unroll
    for (int i = 0; i < 4; ++i)
      av[i] = *(const bf16x8*)&As[(rbase + i * 16 + rl) * 32 + g8];
#pragma unroll
    for (int j = 0; j < 4; ++j)
      bv[j] = *(const bf16x8*)&Bs[(cbase + j * 16 + rl) * 32 + g8];
#pragma unroll
    for (int i = 0; i < 4; ++i)
#pragma unroll
      for (int j = 0; j < 4; ++j)
        acc[i][j] = __builtin_amdgcn_mfma_f32_16x16x32_bf16(av[i], bv[j], acc[i][j], 0, 0, 0);
    __syncthreads();
  }
#pragma unroll
  for (int j = 0; j < 4; ++j) {
    const int n = n0 + cbase + j * 16 + rl;
    const float bj = bias[n];
    const int gate = n >> 10, col = n & 1023;
    const int cri = col >> 6, hcoli = col & 63;
#pragma unroll
    for (int i = 0; i < 4; ++i)
#pragma unroll
      for (int r = 0; r < 4; ++r) {
        const int m = m0 + rbase + i * 16 + gq * 4 + r;
        const int tt = m >> 6, b = m & 63;
        Xp[(size_t)tt * XP_STEP + (size_t)((b >> 4) * 16 + cri) * 4096 +
           gate * 1024 + (b & 15) * 64 + hcoli] = f2bf(acc[i][j][r] + bj);
      }
  }
}

// ---------------------------------------------------------------------------
// Kernel 3: zero h_tag (131072 u32) + flags (64 u32), every launch.
// ---------------------------------------------------------------------------
__global__ void zero_tags(u32* __restrict__ ht) {
  const u32 i = blockIdx.x * 256 + threadIdx.x;
  if (i < 131136u) ht[i] = 0;
}

// ---------------------------------------------------------------------------
// Kernel 4: recurrence. R9 protocol EXACTLY (fire-and-forget tagged stores +
// flag spin + single tag-verified bulk + straggler anchor), 64-block geometry:
// 64 blocks = 4 bg-groups x 16 col-ranges; block owns 16 batches x 64 h-cols.
// Halves aggregate bulk traffic (4MB/step vs 8) and producers/group (16 vs 32).
// 8 waves: wave w -> gate g=w>>1, col-half c2=w&1 (32 cols = 2 n-tiles).
// Per-thread staging identical to R9 (8 x 16B, same swizzles).
// ---------------------------------------------------------------------------
__global__ __launch_bounds__(512, 1) void lstm_rec(
    const u16* __restrict__ Xp, const u16* __restrict__ WhT,
    u32* __restrict__ h_tag, u32* __restrict__ flags, float* __restrict__ out) {
  __shared__ u16 h_lds[16 * 1024]; // [16 rows][1024 k] bf16, XOR-swizzled
  __shared__ float gate_lds[4][4][16][20]; // [gate][col-quarter][row][col16]
  const int tid = threadIdx.x;
  const int lane = tid & 63, w = tid >> 6;
  const int rl = lane & 15, gq = lane >> 4;
  const int cr = blockIdx.x & 15, bg = blockIdx.x >> 4;
  const int g = w >> 1, c2 = w & 1;

  // W_h fragments: 2 n-tiles; cols g*1024 + cr*64 + c2*32 + {0,16} + rl
  bf16x8 wf0[32], wf1[32];
  {
    const size_t gc0 = (size_t)(g * 1024 + cr * 64 + c2 * 32 + rl) * HDIM + gq * 8;
    const size_t gc1 = gc0 + (size_t)16 * HDIM;
#pragma unroll
    for (int kk = 0; kk < 32; ++kk) {
      wf0[kk] = *(const bf16x8*)&WhT[gc0 + kk * 32];
      wf1[kk] = *(const bf16x8*)&WhT[gc1 + kk * 32];
    }
  }

  // elementwise ownership: thread -> (b_el, hc0) and (b_el, hc0+32)
  const int b_el = tid >> 5, hc0 = tid & 31;
  // staging ownership: identical to R9
  const int srow = tid >> 5, s32 = tid & 31;
  const int swz_w = ((srow & 7) << 4) ^ ((srow & 1) << 6);
  const int swz_r = ((rl & 7) << 4) ^ ((rl & 1) << 6);
  float cA = 0.f, hA = 0.f, cB = 0.f, hB = 0.f;

  const u16* xp_p = Xp + (size_t)blockIdx.x * 4096 + b_el * 64 + hc0;
  float xa0 = bf2f(xp_p[0]),    xa1 = bf2f(xp_p[1024]),
        xa2 = bf2f(xp_p[2048]), xa3 = bf2f(xp_p[3072]);
  float xb0 = bf2f(xp_p[32]),   xb1 = bf2f(xp_p[1056]),
        xb2 = bf2f(xp_p[2080]), xb3 = bf2f(xp_p[3104]);

  const u32* flagrow = flags + bg * 16 + (lane & 15); // 16 producers/group

  for (int t = 0; t < T_STEPS; ++t) {
    // prefetch next step's Xp (plain cached; overlaps spin latency)
    u16 na0 = 0, na1 = 0, na2 = 0, na3 = 0, nb0 = 0, nb1 = 0, nb2 = 0, nb3 = 0;
    if (t + 1 < T_STEPS) {
      const u16* p = xp_p + XP_STEP;
      na0 = p[0];  na1 = p[1024]; na2 = p[2048]; na3 = p[3072];
      nb0 = p[32]; nb1 = p[1056]; nb2 = p[2080]; nb3 = p[3104];
    }

    f32x4 aA0 = {0.f, 0.f, 0.f, 0.f}, aA1 = {0.f, 0.f, 0.f, 0.f};
    f32x4 aB0 = {0.f, 0.f, 0.f, 0.f}, aB1 = {0.f, 0.f, 0.f, 0.f};
    if (t > 0) {
      // ---- 1) cheap detect: lanes 0-15 cover the group's 16 flags ----
      for (;;) {
        u32 f = __hip_atomic_load(flagrow, __ATOMIC_RELAXED, __HIP_MEMORY_SCOPE_AGENT);
        if (__all((int)((lane >= 16) | (f >= (u32)t)))) break;
      }
      // ---- 2) single bulk pass: 8 x 16B coherent loads, tag-verified ----
      const u32* hrow32 =
          h_tag + (size_t)(t & 1) * 65536 + (size_t)(bg * 16 + srow) * 1024;
      char* ldsrow = (char*)h_lds + srow * 2048;
      u32x4 v[8];
#pragma unroll
      for (int u = 0; u < 8; ++u)
        v[u] = cload16((const char*)hrow32 + 512 * u + 16 * s32);
      asm volatile("s_waitcnt vmcnt(0)" ::: "memory");
      __builtin_amdgcn_sched_barrier(0);
      u32 pend = 0u;
#pragma unroll
      for (int u = 0; u < 8; ++u) {
        const u32 w0 = v[u][0], w1 = v[u][1], w2 = v[u][2], w3 = v[u][3];
        const u64 packs = (u64)((w0 & 0xffffu) | (w1 << 16)) |
                          ((u64)((w2 & 0xffffu) | (w3 << 16)) << 32);
        *(u64*)(ldsrow + ((256 * u + 8 * s32) ^ swz_w)) = packs;
        if ((w0 >> 16) < (u32)t || (w1 >> 16) < (u32)t ||
            (w2 >> 16) < (u32)t || (w3 >> 16) < (u32)t)
          pend |= (1u << u);
      }
      // rare straggler path (flag/data raced in the fabric)
      while (__builtin_expect(pend != 0u, 0)) {
        const int uu = __ffs(pend) - 1;
        u32x4 q = cload16((const char*)hrow32 + 512 * uu + 16 * s32);
        asm volatile("s_waitcnt vmcnt(0)" ::: "memory");
        const u32 w0 = q[0], w1 = q[1], w2 = q[2], w3 = q[3];
        if ((w0 >> 16) >= (u32)t && (w1 >> 16) >= (u32)t &&
            (w2 >> 16) >= (u32)t && (w3 >> 16) >= (u32)t) {
          const u64 packs = (u64)((w0 & 0xffffu) | (w1 << 16)) |
                            ((u64)((w2 & 0xffffu) | (w3 << 16)) << 32);
          *(u64*)(ldsrow + ((256 * uu + 8 * s32) ^ swz_w)) = packs;
          pend &= pend - 1u;
        }
      }
      __syncthreads();
      const char* hrd = (const char*)h_lds + rl * 2048;
#pragma unroll
      for (int kk = 0; kk < 32; kk += 2) {
        bf16x8 a0 = *(const bf16x8*)(hrd + ((kk * 64 + gq * 16) ^ swz_r));
        bf16x8 a1 = *(const bf16x8*)(hrd + (((kk + 1) * 64 + gq * 16) ^ swz_r));
        aA0 = __builtin_amdgcn_mfma_f32_16x16x32_bf16(a0, wf0[kk], aA0, 0, 0, 0);
        aA1 = __builtin_amdgcn_mfma_f32_16x16x32_bf16(a1, wf0[kk + 1], aA1, 0, 0, 0);
        aB0 = __builtin_amdgcn_mfma_f32_16x16x32_bf16(a0, wf1[kk], aB0, 0, 0, 0);
        aB1 = __builtin_amdgcn_mfma_f32_16x16x32_bf16(a1, wf1[kk + 1], aB1, 0, 0, 0);
      }
      aA0 += aA1;
      aB0 += aB1;
    } else {
      __syncthreads();
    }
    // gate exchange: wave (g,c2) two tiles -> quarters c2*2, c2*2+1
#pragma unroll
    for (int r = 0; r < 4; ++r) {
      gate_lds[g][c2 * 2][gq * 4 + r][rl] = aA0[r];
      gate_lds[g][c2 * 2 + 1][gq * 4 + r][rl] = aB0[r];
    }
    __syncthreads();
    // elementwise: thread owns (b_el, hc0) and (b_el, hc0+32)
    {
      const int q = hc0 >> 4, cl = hc0 & 15;
      const float giA = gate_lds[0][q][b_el][cl] + xa0;
      const float gfA = gate_lds[1][q][b_el][cl] + xa1;
      const float ggA = gate_lds[2][q][b_el][cl] + xa2;
      const float goA = gate_lds[3][q][b_el][cl] + xa3;
      cA = sigm(gfA) * cA + sigm(giA) * tanh_fast(ggA);
      hA = sigm(goA) * tanh_fast(cA);
      const float giB = gate_lds[0][q + 2][b_el][cl] + xb0;
      const float gfB = gate_lds[1][q + 2][b_el][cl] + xb1;
      const float ggB = gate_lds[2][q + 2][b_el][cl] + xb2;
      const float goB = gate_lds[3][q + 2][b_el][cl] + xb3;
      cB = sigm(gfB) * cB + sigm(giB) * tanh_fast(ggB);
      hB = sigm(goB) * tanh_fast(cB);
      // tagged h stores FIRST (critical path), fire-and-forget
      const size_t hb = (size_t)((t + 1) & 1) * 65536 +
                        (size_t)(bg * 16 + b_el) * 1024 + cr * 64 + hc0;
      __hip_atomic_store(&h_tag[hb], (u32)f2bf(hA) | ((u32)(t + 1) << 16),
                         __ATOMIC_RELAXED, __HIP_MEMORY_SCOPE_AGENT);
      __hip_atomic_store(&h_tag[hb + 32], (u32)f2bf(hB) | ((u32)(t + 1) << 16),
                         __ATOMIC_RELAXED, __HIP_MEMORY_SCOPE_AGENT);
    }
    // readiness flag: immediately after h stores, no ordering ops
    if (tid == 0)
      __hip_atomic_store(&flags[bg * 16 + cr], (u32)(t + 1), __ATOMIC_RELAXED,
                         __HIP_MEMORY_SCOPE_AGENT);
    // out stores after (off the critical path)
    {
      const size_t ob = ((size_t)t * BATCH + bg * 16 + b_el) * HDIM + cr * 64 + hc0;
      out[ob] = hA;
      out[ob + 32] = hB;
    }
    xa0 = bf2f(na0); xa1 = bf2f(na1); xa2 = bf2f(na2); xa3 = bf2f(na3);
    xb0 = bf2f(nb0); xb1 = bf2f(nb1); xb2 = bf2f(nb2); xb3 = bf2f(nb3);
    xp_p += XP_STEP;
  }
  // hT, cT
  {
    const size_t tb = (size_t)HS_ELEMS + (size_t)(bg * 16 + b_el) * HDIM + cr * 64 + hc0;
    out[tb] = hA;
    out[tb + 32] = hB;
    out[tb + 65536u] = cA;
    out[tb + 65536u + 32] = cB;
  }
}

// ---------------------------------------------------------------------------
// Workspace layout (bytes), serialized R9 structure:
//   [0,        524288)    h_tag: 2 slots x 64 x 1024 u32 (aliases WxT region)
//   [524288,   524544)    flags: 64 u32
//   [0,        8388608)   WxT (gemm only; dead before zero_tags runs)
//   [8388608,  16777216)  WhT [4096][1024] bf16
//   [16777216, +256MB)    Xp blocked [512][64][4][1024] u16
// Xbf (64MB) at d_out base: written by convert_x, read by gemm_xp, then
// overwritten by lstm_rec's out stores (stream-ordered, deterministic).
// ---------------------------------------------------------------------------
extern "C" void kernel_launch(void* const* d_in, const int* in_sizes, int n_in,
                              void* d_out, int out_size, void* d_ws, size_t ws_size,
                              hipStream_t stream) {
  const float* x = (const float*)d_in[0];
  const float* Wx = (const float*)d_in[1];
  const float* Wh = (const float*)d_in[2];
  const float* bias = (const float*)d_in[3];
  float* out = (float*)d_out;
  char* ws = (char*)d_ws;

  u16* WxT = (u16*)(ws + 0);
  u32* h_tag = (u32*)(ws + 0);      // aliases WxT; live only after zero_tags
  u32* flags = (u32*)(ws + 524288); // ditto
  u16* WhT = (u16*)(ws + 8388608);
  u16* Xp = (u16*)(ws + 16777216);
  u16* Xbf = (u16*)d_out; // scratch in d_out, dead after gemm_xp

  transpose_w<<<dim3(128, 32, 2), dim3(32, 8), 0, stream>>>(Wx, Wh, WxT, WhT);
  convert_x<<<dim3(16384), dim3(256), 0, stream>>>(x, Xbf);
  gemm_xp<<<dim3(8192), dim3(256), 0, stream>>>(Xbf, WxT, bias, Xp);
  zero_tags<<<dim3(513), dim3(256), 0, stream>>>(h_tag);
  lstm_rec<<<dim3(64), dim3(512), 0, stream>>>(Xp, WhT, h_tag, flags, out);
}

// Round 15
// 3189.657 us; speedup vs baseline: 1.8084x; 1.8084x over previous
//
#include <hip/hip_runtime.h>

typedef unsigned short u16;
typedef unsigned int u32;
typedef unsigned long long u64;
typedef float f32x4 __attribute__((ext_vector_type(4)));
typedef __bf16 bf16x8 __attribute__((ext_vector_type(8)));
typedef u16 u16x8 __attribute__((ext_vector_type(8)));
typedef u32 u32x4 __attribute__((ext_vector_type(4)));

#define T_STEPS 512
#define BATCH 64
#define HDIM 1024
#define GDIM 4096            // 4*H
#define HS_ELEMS (33554432u) // 512*64*1024
#define XP_STEP 262144       // u16 per t: 128 blk * 4 gate * 512

__device__ __forceinline__ u16 f2bf(float f) {
  union { float f; u32 u; } v; v.f = f;
  u32 r = v.u + 0x7fffu + ((v.u >> 16) & 1u);
  return (u16)(r >> 16);
}
__device__ __forceinline__ float bf2f(u16 b) {
  union { u32 u; float f; } v; v.u = ((u32)b) << 16;
  return v.f;
}
__device__ __forceinline__ float sigm(float x) { return 1.f / (1.f + __expf(-x)); }
__device__ __forceinline__ float tanh_fast(float x) { return 1.f - 2.f / (__expf(2.f * x) + 1.f); }

// async global->LDS, 16B per lane
__device__ __forceinline__ void gload16(const void* g, void* l) {
  __builtin_amdgcn_global_load_lds(
      (const __attribute__((address_space(1))) u32*)g,
      (__attribute__((address_space(3))) u32*)l, 16, 0, 0);
}
// LLC-coherent 16B load (bypass L1+L2; agent scope)
__device__ __forceinline__ u32x4 cload16(const void* g) {
  u32x4 r;
  asm volatile("global_load_dwordx4 %0, %1, off sc0 sc1" : "=&v"(r) : "v"(g) : "memory");
  return r;
}

// ---------------------------------------------------------------------------
// Kernel 1: fused prep. Flat grid of 25089 x 256:
//   [0,     8192): transpose+convert W (z = b>>12, 4096 blocks per matrix)
//   [8192, 24576): convert X fp32->bf16 into d_out scratch
//   [24576,25089): zero h_tag+flags (131328 u32) -- only when do_zero != 0
// ---------------------------------------------------------------------------
__global__ void prep(const float* __restrict__ Wx, const float* __restrict__ Wh,
                     u16* __restrict__ WxT, u16* __restrict__ WhT,
                     const float* __restrict__ X, u16* __restrict__ Xbf,
                     u32* __restrict__ h_tag, int do_zero) {
  __shared__ float tile[32][33];
  const int b = blockIdx.x, tid = threadIdx.x;
  if (b < 8192) {
    const int z = b >> 12, rem = b & 4095;
    const int n0 = (rem & 127) * 32, k0 = (rem >> 7) * 32;
    const float* src = z ? Wh : Wx;
    u16* dst = z ? WhT : WxT;
    const int tx = tid & 31, ty = tid >> 5;
#pragma unroll
    for (int i = 0; i < 4; ++i)
      tile[ty + i * 8][tx] = src[(size_t)(k0 + ty + i * 8) * GDIM + n0 + tx];
    __syncthreads();
#pragma unroll
    for (int i = 0; i < 4; ++i)
      dst[(size_t)(n0 + ty + i * 8) * HDIM + k0 + tx] = f2bf(tile[tx][ty + i * 8]);
  } else if (b < 24576) {
    const size_t i = ((size_t)(b - 8192) * 256 + tid) * 8;
    const float4 a = *(const float4*)&X[i];
    const float4 c = *(const float4*)&X[i + 4];
    u16x8 o;
    o[0] = f2bf(a.x); o[1] = f2bf(a.y); o[2] = f2bf(a.z); o[3] = f2bf(a.w);
    o[4] = f2bf(c.x); o[5] = f2bf(c.y); o[6] = f2bf(c.z); o[7] = f2bf(c.w);
    *(u16x8*)&Xbf[i] = o;
  } else if (do_zero) {
    const u32 j = (u32)(b - 24576) * 256 + tid;
    if (j < 131328u) h_tag[j] = 0;
  }
}

// fallback zero kernel (used only if ws too small for non-aliased h_tag)
__global__ void zero_tags(u32* __restrict__ ht) {
  const u32 i = blockIdx.x * 256 + threadIdx.x;
  if (i < 131328u) ht[i] = 0;
}

// ---------------------------------------------------------------------------
// Kernel 2: Xp = bf16(Xbf @ W_x + b), m97-style (R9-proven ~300us).
// Epilogue blocked: Xp[t][blk=bg*32+cr][gate][b_el*32+hcol].
// ---------------------------------------------------------------------------
__global__ __launch_bounds__(256) void gemm_xp(
    const u16* __restrict__ Xbf, const u16* __restrict__ WxT,
    const float* __restrict__ bias, u16* __restrict__ Xp) {
  __shared__ u16 As[128 * 32];
  __shared__ u16 Bs[128 * 32];
  const int tid = threadIdx.x;
  const int lane = tid & 63, w = tid >> 6;
  const int rl = lane & 15, gq = lane >> 4, g8 = gq * 8;
  const int swz = (blockIdx.x & 7) * 1024 + (blockIdx.x >> 3);
  const int m0 = (swz >> 5) * 128, n0 = (swz & 31) * 128;
  const int rbase = (w >> 1) * 64, cbase = (w & 1) * 64;
  const int r0 = tid >> 2, c0 = (tid & 3) * 8;

  f32x4 acc[4][4] = {};
  for (int k0 = 0; k0 < 1024; k0 += 32) {
    gload16(&Xbf[(size_t)(m0 + r0) * 1024 + k0 + c0], &As[w * 512]);
    gload16(&Xbf[(size_t)(m0 + r0 + 64) * 1024 + k0 + c0], &As[2048 + w * 512]);
    gload16(&WxT[(size_t)(n0 + r0) * 1024 + k0 + c0], &Bs[w * 512]);
    gload16(&WxT[(size_t)(n0 + r0 + 64) * 1024 + k0 + c0], &Bs[2048 + w * 512]);
    __syncthreads();
    bf16x8 av[4], bv[4];
#pragma unroll
    for (int i = 0; i < 4; ++i)
      av[i] = *(const bf16x8*)&As[(rbase + i * 16 + rl) * 32 + g8];
#pragma unroll
    for (int j = 0; j < 4; ++j)
      bv[j] = *(const bf16x8*)&Bs[(cbase + j * 16 + rl) * 32 + g8];
#pragma unroll
    for (int i = 0; i < 4; ++i)
#pragma unroll
      for (int j = 0; j < 4; ++j)
        acc[i][j] = __builtin_amdgcn_mfma_f32_16x16x32_bf16(av[i], bv[j], acc[i][j], 0, 0, 0);
    __syncthreads();
  }
#pragma unroll
  for (int j = 0; j < 4; ++j) {
    const int n = n0 + cbase + j * 16 + rl;
    const float bj = bias[n];
    const int gate = n >> 10, col = n & 1023;
    const int cri = col >> 5, hcoli = col & 31;
#pragma unroll
    for (int i = 0; i < 4; ++i)
#pragma unroll
      for (int r = 0; r < 4; ++r) {
        const int m = m0 + rbase + i * 16 + gq * 4 + r;
        const int tt = m >> 6, b = m & 63;
        Xp[(size_t)tt * XP_STEP + (size_t)((b >> 4) * 32 + cri) * 2048 +
           gate * 512 + (b & 15) * 32 + hcoli] = f2bf(acc[i][j][r] + bj);
      }
  }
}

// ---------------------------------------------------------------------------
// Kernel 3: recurrence. R9 protocol (fire-and-forget tagged stores + flag
// spin + tag-verified bulk + straggler anchor), 128 blk x 512 thr geometry,
// with HALF-SPLIT staging pipeline:
//   spin flags[0..15] -> bulk u0..3 -> stage lower LDS
//   spin flags[16..31] -> ISSUE u4..7 (stay in flight)
//   lgkmcnt(0)+raw s_barrier (no vmcnt drain) -> MFMA kk=0..15 (cols 0..511)
//   vmcnt(0) -> stage upper LDS (disjoint region) -> raw barrier -> kk=16..31
// ---------------------------------------------------------------------------
__global__ __launch_bounds__(512, 1) void lstm_rec(
    const u16* __restrict__ Xp, const u16* __restrict__ WhT,
    u32* __restrict__ h_tag, u32* __restrict__ flags, float* __restrict__ out) {
  __shared__ u16 h_lds[16 * 1024]; // [16 rows][1024 k] bf16, XOR-swizzled
  __shared__ float gate_lds[4][2][16][20];
  const int tid = threadIdx.x;
  const int lane = tid & 63, w = tid >> 6;
  const int rl = lane & 15, gq = lane >> 4;
  const int cr = blockIdx.x & 31, bg = blockIdx.x >> 5;
  const int g = w >> 1, c2 = w & 1;

  // W_h fragments (wave (g,c2): cols g*1024 + cr*32 + c2*16 + rl)
  bf16x8 wf[32];
  {
    const size_t gcol = (size_t)(g * 1024 + cr * 32 + c2 * 16 + rl) * HDIM + gq * 8;
#pragma unroll
    for (int kk = 0; kk < 32; ++kk)
      wf[kk] = *(const bf16x8*)&WhT[gcol + kk * 32];
  }

  const int b_el = tid >> 5, hcol = tid & 31;
  const int srow = tid >> 5, s32 = tid & 31;
  const int swz_w = ((srow & 7) << 4) ^ ((srow & 1) << 6);
  const int swz_r = ((rl & 7) << 4) ^ ((rl & 1) << 6);
  float creg = 0.f, hreg = 0.f;

  const u16* xp_p = Xp + (size_t)blockIdx.x * 2048 + tid;
  float xg0 = bf2f(xp_p[0]), xg1 = bf2f(xp_p[512]),
        xg2 = bf2f(xp_p[1024]), xg3 = bf2f(xp_p[1536]);

  const u32* flag_lo = flags + bg * 32 + (lane & 15);
  const u32* flag_hi = flag_lo + 16;

  for (int t = 0; t < T_STEPS; ++t) {
    // prefetch next step's Xp (plain cached; overlaps spin latency)
    u16 nx0 = 0, nx1 = 0, nx2 = 0, nx3 = 0;
    if (t + 1 < T_STEPS) {
      const u16* p = xp_p + XP_STEP;
      nx0 = p[0]; nx1 = p[512]; nx2 = p[1024]; nx3 = p[1536];
    }

    f32x4 acc0 = {0.f, 0.f, 0.f, 0.f}, acc1 = {0.f, 0.f, 0.f, 0.f};
    if (t > 0) {
      const u32* hrow32 =
          h_tag + (size_t)(t & 1) * 65536 + (size_t)(bg * 16 + srow) * 1024;
      char* ldsrow = (char*)h_lds + srow * 2048;
      // ---- spin half1 (producers cr 0..15 -> h cols 0..511) ----
      for (;;) {
        u32 f = __hip_atomic_load(flag_lo, __ATOMIC_RELAXED, __HIP_MEMORY_SCOPE_AGENT);
        if (__all((int)(f >= (u32)t))) break;
      }
      // ---- bulk u0..3, tag-verified, stage lower LDS region ----
      {
        u32x4 v[4];
#pragma unroll
        for (int u = 0; u < 4; ++u)
          v[u] = cload16((const char*)hrow32 + 512 * u + 16 * s32);
        asm volatile("s_waitcnt vmcnt(0)" ::: "memory");
        __builtin_amdgcn_sched_barrier(0);
        u32 pend = 0u;
#pragma unroll
        for (int u = 0; u < 4; ++u) {
          const u32 w0 = v[u][0], w1 = v[u][1], w2 = v[u][2], w3 = v[u][3];
          const u64 packs = (u64)((w0 & 0xffffu) | (w1 << 16)) |
                            ((u64)((w2 & 0xffffu) | (w3 << 16)) << 32);
          *(u64*)(ldsrow + ((256 * u + 8 * s32) ^ swz_w)) = packs;
          if ((w0 >> 16) < (u32)t || (w1 >> 16) < (u32)t ||
              (w2 >> 16) < (u32)t || (w3 >> 16) < (u32)t)
            pend |= (1u << u);
        }
        while (__builtin_expect(pend != 0u, 0)) {
          const int uu = __ffs(pend) - 1;
          u32x4 q = cload16((const char*)hrow32 + 512 * uu + 16 * s32);
          asm volatile("s_waitcnt vmcnt(0)" ::: "memory");
          const u32 w0 = q[0], w1 = q[1], w2 = q[2], w3 = q[3];
          if ((w0 >> 16) >= (u32)t && (w1 >> 16) >= (u32)t &&
              (w2 >> 16) >= (u32)t && (w3 >> 16) >= (u32)t) {
            const u64 packs = (u64)((w0 & 0xffffu) | (w1 << 16)) |
                              ((u64)((w2 & 0xffffu) | (w3 << 16)) << 32);
            *(u64*)(ldsrow + ((256 * uu + 8 * s32) ^ swz_w)) = packs;
            pend &= pend - 1u;
          }
        }
      }
      // ---- spin half2, then ISSUE u4..7 (left in flight) ----
      for (;;) {
        u32 f = __hip_atomic_load(flag_hi, __ATOMIC_RELAXED, __HIP_MEMORY_SCOPE_AGENT);
        if (__all((int)(f >= (u32)t))) break;
      }
      u32x4 v2[4];
#pragma unroll
      for (int u = 0; u < 4; ++u)
        v2[u] = cload16((const char*)hrow32 + 512 * (u + 4) + 16 * s32);
      // barrier for half1 LDS visibility WITHOUT draining vmcnt
      asm volatile("s_waitcnt lgkmcnt(0)" ::: "memory");
      __builtin_amdgcn_sched_barrier(0);
      __builtin_amdgcn_s_barrier();
      // ---- MFMA first half (cols 0..511) while u4..7 fly ----
      const char* hrd = (const char*)h_lds + rl * 2048;
#pragma unroll
      for (int kk = 0; kk < 16; kk += 2) {
        bf16x8 a0 = *(const bf16x8*)(hrd + ((kk * 64 + gq * 16) ^ swz_r));
        bf16x8 a1 = *(const bf16x8*)(hrd + (((kk + 1) * 64 + gq * 16) ^ swz_r));
        acc0 = __builtin_amdgcn_mfma_f32_16x16x32_bf16(a0, wf[kk], acc0, 0, 0, 0);
        acc1 = __builtin_amdgcn_mfma_f32_16x16x32_bf16(a1, wf[kk + 1], acc1, 0, 0, 0);
      }
      // ---- drain u4..7, stage upper LDS region (disjoint from lower) ----
      asm volatile("s_waitcnt vmcnt(0)" ::: "memory");
      __builtin_amdgcn_sched_barrier(0);
      {
        u32 pend = 0u;
#pragma unroll
        for (int u = 0; u < 4; ++u) {
          const u32 w0 = v2[u][0], w1 = v2[u][1], w2 = v2[u][2], w3 = v2[u][3];
          const u64 packs = (u64)((w0 & 0xffffu) | (w1 << 16)) |
                            ((u64)((w2 & 0xffffu) | (w3 << 16)) << 32);
          *(u64*)(ldsrow + ((256 * (u + 4) + 8 * s32) ^ swz_w)) = packs;
          if ((w0 >> 16) < (u32)t || (w1 >> 16) < (u32)t ||
              (w2 >> 16) < (u32)t || (w3 >> 16) < (u32)t)
            pend |= (1u << u);
        }
        while (__builtin_expect(pend != 0u, 0)) {
          const int uu = __ffs(pend) - 1;
          u32x4 q = cload16((const char*)hrow32 + 512 * (uu + 4) + 16 * s32);
          asm volatile("s_waitcnt vmcnt(0)" ::: "memory");
          const u32 w0 = q[0], w1 = q[1], w2 = q[2], w3 = q[3];
          if ((w0 >> 16) >= (u32)t && (w1 >> 16) >= (u32)t &&
              (w2 >> 16) >= (u32)t && (w3 >> 16) >= (u32)t) {
            const u64 packs = (u64)((w0 & 0xffffu) | (w1 << 16)) |
                              ((u64)((w2 & 0xffffu) | (w3 << 16)) << 32);
            *(u64*)(ldsrow + ((256 * (uu + 4) + 8 * s32) ^ swz_w)) = packs;
            pend &= pend - 1u;
          }
        }
      }
      asm volatile("s_waitcnt lgkmcnt(0)" ::: "memory");
      __builtin_amdgcn_sched_barrier(0);
      __builtin_amdgcn_s_barrier();
      // ---- MFMA second half (cols 512..1023) ----
#pragma unroll
      for (int kk = 16; kk < 32; kk += 2) {
        bf16x8 a0 = *(const bf16x8*)(hrd + ((kk * 64 + gq * 16) ^ swz_r));
        bf16x8 a1 = *(const bf16x8*)(hrd + (((kk + 1) * 64 + gq * 16) ^ swz_r));
        acc0 = __builtin_amdgcn_mfma_f32_16x16x32_bf16(a0, wf[kk], acc0, 0, 0, 0);
        acc1 = __builtin_amdgcn_mfma_f32_16x16x32_bf16(a1, wf[kk + 1], acc1, 0, 0, 0);
      }
      acc0 += acc1;
    } else {
      __syncthreads();
    }
    // gate exchange: wave (g,c2) tile -> C[row=gq*4+r][col=rl]
#pragma unroll
    for (int r = 0; r < 4; ++r)
      gate_lds[g][c2][gq * 4 + r][rl] = acc0[r];
    __syncthreads();
    // elementwise: thread owns (b_el, hcol)
    {
      const int cq = hcol >> 4, cl = hcol & 15;
      const float gi = gate_lds[0][cq][b_el][cl] + xg0;
      const float gf = gate_lds[1][cq][b_el][cl] + xg1;
      const float gg = gate_lds[2][cq][b_el][cl] + xg2;
      const float go = gate_lds[3][cq][b_el][cl] + xg3;
      const float iv = sigm(gi);
      const float fv = sigm(gf);
      const float gv = tanh_fast(gg);
      const float ov = sigm(go);
      creg = fv * creg + iv * gv;
      hreg = ov * tanh_fast(creg);
      // tagged h store FIRST (critical path), fire-and-forget
      const u32 wv = (u32)f2bf(hreg) | ((u32)(t + 1) << 16);
      __hip_atomic_store(
          &h_tag[(size_t)((t + 1) & 1) * 65536 + (size_t)(bg * 16 + b_el) * 1024 + cr * 32 + hcol],
          wv, __ATOMIC_RELAXED, __HIP_MEMORY_SCOPE_AGENT);
    }
    // readiness flag: immediately after h stores, no ordering ops
    if (tid == 0)
      __hip_atomic_store(&flags[bg * 32 + cr], (u32)(t + 1), __ATOMIC_RELAXED,
                         __HIP_MEMORY_SCOPE_AGENT);
    // out store after (off the critical path)
    out[((size_t)t * BATCH + bg * 16 + b_el) * HDIM + cr * 32 + hcol] = hreg;
    xg0 = bf2f(nx0); xg1 = bf2f(nx1); xg2 = bf2f(nx2); xg3 = bf2f(nx3);
    xp_p += XP_STEP;
  }
  // hT, cT
  out[(size_t)HS_ELEMS + (size_t)(bg * 16 + b_el) * HDIM + cr * 32 + hcol] = hreg;
  out[(size_t)HS_ELEMS + 65536u + (size_t)(bg * 16 + b_el) * HDIM + cr * 32 + hcol] = creg;
}

// ---------------------------------------------------------------------------
// Workspace: [0,8MB) WxT | [8,16MB) WhT | [16,272MB) Xp blocked.
// BIG mode (ws_size >= 272MB+513KB; R12 proved available): h_tag at ws+272MB,
//   flags = h_tag+131072; zeroed pre-gemm inside prep (no WxT alias).
// SMALL fallback: h_tag aliases WxT, zeroed post-gemm (R9 behavior).
// d_out scratch: Xbf (64MB) at d_out base; written by prep, read by gemm,
// then overwritten by lstm_rec's out stores (stream-ordered).
// ---------------------------------------------------------------------------
extern "C" void kernel_launch(void* const* d_in, const int* in_sizes, int n_in,
                              void* d_out, int out_size, void* d_ws, size_t ws_size,
                              hipStream_t stream) {
  const float* x = (const float*)d_in[0];
  const float* Wx = (const float*)d_in[1];
  const float* Wh = (const float*)d_in[2];
  const float* bias = (const float*)d_in[3];
  float* out = (float*)d_out;
  char* ws = (char*)d_ws;

  u16* WxT = (u16*)(ws + 0);
  u16* WhT = (u16*)(ws + 8388608);
  u16* Xp = (u16*)(ws + 16777216);
  u16* Xbf = (u16*)d_out; // scratch in d_out, dead after gemm_xp

  const bool big = ws_size >= (size_t)(285212672 + 525312);
  u32* h_tag = big ? (u32*)(ws + 285212672) : (u32*)ws;
  u32* flags = h_tag + 131072;

  prep<<<dim3(25089), dim3(256), 0, stream>>>(Wx, Wh, WxT, WhT, x, Xbf, h_tag,
                                              big ? 1 : 0);
  gemm_xp<<<dim3(8192), dim3(256), 0, stream>>>(Xbf, WxT, bias, Xp);
  if (!big) zero_tags<<<dim3(513), dim3(256), 0, stream>>>(h_tag);
  lstm_rec<<<dim3(128), dim3(512), 0, stream>>>(Xp, WhT, h_tag, flags, out);
}

// Round 16
// 2260.510 us; speedup vs baseline: 2.5517x; 1.4110x over previous
//
#include <hip/hip_runtime.h>

typedef unsigned short u16;
typedef unsigned int u32;
typedef unsigned long long u64;
typedef float f32x4 __attribute__((ext_vector_type(4)));
typedef __bf16 bf16x8 __attribute__((ext_vector_type(8)));
typedef u16 u16x8 __attribute__((ext_vector_type(8)));
typedef u32 u32x4 __attribute__((ext_vector_type(4)));

#define T_STEPS 512
#define BATCH 64
#define HDIM 1024
#define GDIM 4096            // 4*H
#define HS_ELEMS (33554432u) // 512*64*1024
#define XP_STEP 262144       // u16 per t: 128 blk * 4 gate * 512

__device__ __forceinline__ u16 f2bf(float f) {
  union { float f; u32 u; } v; v.f = f;
  u32 r = v.u + 0x7fffu + ((v.u >> 16) & 1u);
  return (u16)(r >> 16);
}
__device__ __forceinline__ float bf2f(u16 b) {
  union { u32 u; float f; } v; v.u = ((u32)b) << 16;
  return v.f;
}
__device__ __forceinline__ float sigm(float x) { return 1.f / (1.f + __expf(-x)); }
__device__ __forceinline__ float tanh_fast(float x) { return 1.f - 2.f / (__expf(2.f * x) + 1.f); }

// async global->LDS, 16B per lane
__device__ __forceinline__ void gload16(const void* g, void* l) {
  __builtin_amdgcn_global_load_lds(
      (const __attribute__((address_space(1))) u32*)g,
      (__attribute__((address_space(3))) u32*)l, 16, 0, 0);
}
// LLC-coherent 16B load (bypass L1+L2; agent scope)
__device__ __forceinline__ u32x4 cload16(const void* g) {
  u32x4 r;
  asm volatile("global_load_dwordx4 %0, %1, off sc0 sc1" : "=&v"(r) : "v"(g) : "memory");
  return r;
}

// ---------------------------------------------------------------------------
// Kernel 1: fused prep (R15-proven). Flat grid of 25089 x 256:
//   [0,     8192): transpose+convert W (z = b>>12, 4096 blocks per matrix)
//   [8192, 24576): convert X fp32->bf16 into d_out scratch
//   [24576,25089): zero h_tag+flags (131328 u32) -- only when do_zero != 0
// ---------------------------------------------------------------------------
__global__ void prep(const float* __restrict__ Wx, const float* __restrict__ Wh,
                     u16* __restrict__ WxT, u16* __restrict__ WhT,
                     const float* __restrict__ X, u16* __restrict__ Xbf,
                     u32* __restrict__ h_tag, int do_zero) {
  __shared__ float tile[32][33];
  const int b = blockIdx.x, tid = threadIdx.x;
  if (b < 8192) {
    const int z = b >> 12, rem = b & 4095;
    const int n0 = (rem & 127) * 32, k0 = (rem >> 7) * 32;
    const float* src = z ? Wh : Wx;
    u16* dst = z ? WhT : WxT;
    const int tx = tid & 31, ty = tid >> 5;
#pragma unroll
    for (int i = 0; i < 4; ++i)
      tile[ty + i * 8][tx] = src[(size_t)(k0 + ty + i * 8) * GDIM + n0 + tx];
    __syncthreads();
#pragma unroll
    for (int i = 0; i < 4; ++i)
      dst[(size_t)(n0 + ty + i * 8) * HDIM + k0 + tx] = f2bf(tile[tx][ty + i * 8]);
  } else if (b < 24576) {
    const size_t i = ((size_t)(b - 8192) * 256 + tid) * 8;
    const float4 a = *(const float4*)&X[i];
    const float4 c = *(const float4*)&X[i + 4];
    u16x8 o;
    o[0] = f2bf(a.x); o[1] = f2bf(a.y); o[2] = f2bf(a.z); o[3] = f2bf(a.w);
    o[4] = f2bf(c.x); o[5] = f2bf(c.y); o[6] = f2bf(c.z); o[7] = f2bf(c.w);
    *(u16x8*)&Xbf[i] = o;
  } else if (do_zero) {
    const u32 j = (u32)(b - 24576) * 256 + tid;
    if (j < 131328u) h_tag[j] = 0;
  }
}

// fallback zero kernel (used only if ws too small for non-aliased h_tag)
__global__ void zero_tags(u32* __restrict__ ht) {
  const u32 i = blockIdx.x * 256 + threadIdx.x;
  if (i < 131328u) ht[i] = 0;
}

// ---------------------------------------------------------------------------
// Kernel 2: Xp = bf16(Xbf @ W_x + b), m97-style (R9-proven ~300us).
// Epilogue blocked: Xp[t][blk=bg*32+cr][gate][b_el*32+hcol].
// ---------------------------------------------------------------------------
__global__ __launch_bounds__(256) void gemm_xp(
    const u16* __restrict__ Xbf, const u16* __restrict__ WxT,
    const float* __restrict__ bias, u16* __restrict__ Xp) {
  __shared__ u16 As[128 * 32];
  __shared__ u16 Bs[128 * 32];
  const int tid = threadIdx.x;
  const int lane = tid & 63, w = tid >> 6;
  const int rl = lane & 15, gq = lane >> 4, g8 = gq * 8;
  const int swz = (blockIdx.x & 7) * 1024 + (blockIdx.x >> 3);
  const int m0 = (swz >> 5) * 128, n0 = (swz & 31) * 128;
  const int rbase = (w >> 1) * 64, cbase = (w & 1) * 64;
  const int r0 = tid >> 2, c0 = (tid & 3) * 8;

  f32x4 acc[4][4] = {};
  for (int k0 = 0; k0 < 1024; k0 += 32) {
    gload16(&Xbf[(size_t)(m0 + r0) * 1024 + k0 + c0], &As[w * 512]);
    gload16(&Xbf[(size_t)(m0 + r0 + 64) * 1024 + k0 + c0], &As[2048 + w * 512]);
    gload16(&WxT[(size_t)(n0 + r0) * 1024 + k0 + c0], &Bs[w * 512]);
    gload16(&WxT[(size_t)(n0 + r0 + 64) * 1024 + k0 + c0], &Bs[2048 + w * 512]);
    __syncthreads();
    bf16x8 av[4], bv[4];
#pragma unroll
    for (int i = 0; i < 4; ++i)
      av[i] = *(const bf16x8*)&As[(rbase + i * 16 + rl) * 32 + g8];
#pragma unroll
    for (int j = 0; j < 4; ++j)
      bv[j] = *(const bf16x8*)&Bs[(cbase + j * 16 + rl) * 32 + g8];
#pragma unroll
    for (int i = 0; i < 4; ++i)
#pragma unroll
      for (int j = 0; j < 4; ++j)
        acc[i][j] = __builtin_amdgcn_mfma_f32_16x16x32_bf16(av[i], bv[j], acc[i][j], 0, 0, 0);
    __syncthreads();
  }
#pragma unroll
  for (int j = 0; j < 4; ++j) {
    const int n = n0 + cbase + j * 16 + rl;
    const float bj = bias[n];
    const int gate = n >> 10, col = n & 1023;
    const int cri = col >> 5, hcoli = col & 31;
#pragma unroll
    for (int i = 0; i < 4; ++i)
#pragma unroll
      for (int r = 0; r < 4; ++r) {
        const int m = m0 + rbase + i * 16 + gq * 4 + r;
        const int tt = m >> 6, b = m & 63;
        Xp[(size_t)tt * XP_STEP + (size_t)((b >> 4) * 32 + cri) * 2048 +
           gate * 512 + (b & 15) * 32 + hcoli] = f2bf(acc[i][j][r] + bj);
      }
  }
}

// ---------------------------------------------------------------------------
// Kernel 3: recurrence — R9 EXACT (best measured: 1.83ms).
// 128 blocks = 4 bg-groups x 32 col-ranges. Tagged dataflow:
// Producer: tagged h stores (u32 = (t+1)<<16 | bf16) fire-and-forget, then
//   tid==0 raises flags[bg*32+cr]=t+1 (no ordering ops; tags are the net).
// Consumer: tight flag spin -> ONE tag-verified bulk pass (8 x 16B coherent
//   loads) -> swizzled LDS -> MFMA; per-word straggler loop as anchor.
// ---------------------------------------------------------------------------
__global__ __launch_bounds__(512, 1) void lstm_rec(
    const u16* __restrict__ Xp, const u16* __restrict__ WhT,
    u32* __restrict__ h_tag, u32* __restrict__ flags, float* __restrict__ out) {
  __shared__ u16 h_lds[16 * 1024]; // [16 rows][1024 k] bf16, XOR-swizzled
  __shared__ float gate_lds[4][2][16][20];
  const int tid = threadIdx.x;
  const int lane = tid & 63, w = tid >> 6;
  const int rl = lane & 15, gq = lane >> 4;
  const int cr = blockIdx.x & 31, bg = blockIdx.x >> 5;
  const int g = w >> 1, c2 = w & 1;

  // W_h fragments (wave (g,c2): cols g*1024 + cr*32 + c2*16 + rl)
  bf16x8 wf[32];
  {
    const size_t gcol = (size_t)(g * 1024 + cr * 32 + c2 * 16 + rl) * HDIM + gq * 8;
#pragma unroll
    for (int kk = 0; kk < 32; ++kk)
      wf[kk] = *(const bf16x8*)&WhT[gcol + kk * 32];
  }

  const int b_el = tid >> 5, hcol = tid & 31;
  const int srow = tid >> 5, s32 = tid & 31;
  const int swz_w = ((srow & 7) << 4) ^ ((srow & 1) << 6);
  const int swz_r = ((rl & 7) << 4) ^ ((rl & 1) << 6);
  float creg = 0.f, hreg = 0.f;

  const u16* xp_p = Xp + (size_t)blockIdx.x * 2048 + tid;
  float xg0 = bf2f(xp_p[0]), xg1 = bf2f(xp_p[512]),
        xg2 = bf2f(xp_p[1024]), xg3 = bf2f(xp_p[1536]);

  const u32* flagrow = flags + bg * 32 + (lane & 31);

  for (int t = 0; t < T_STEPS; ++t) {
    // prefetch next step's Xp (plain cached; overlaps spin latency)
    u16 nx0 = 0, nx1 = 0, nx2 = 0, nx3 = 0;
    if (t + 1 < T_STEPS) {
      const u16* p = xp_p + XP_STEP;
      nx0 = p[0]; nx1 = p[512]; nx2 = p[1024]; nx3 = p[1536];
    }

    f32x4 acc0 = {0.f, 0.f, 0.f, 0.f}, acc1 = {0.f, 0.f, 0.f, 0.f};
    if (t > 0) {
      // ---- 1) cheap detect: 1 flag load per lane per spin iter ----
      for (;;) {
        u32 f = __hip_atomic_load(flagrow, __ATOMIC_RELAXED, __HIP_MEMORY_SCOPE_AGENT);
        if (__all((int)(f >= (u32)t))) break;
      }
      // ---- 2) single bulk pass: 8 x 16B coherent loads, tag-verified ----
      const u32* hrow32 =
          h_tag + (size_t)(t & 1) * 65536 + (size_t)(bg * 16 + srow) * 1024;
      char* ldsrow = (char*)h_lds + srow * 2048;
      u32x4 v[8];
#pragma unroll
      for (int u = 0; u < 8; ++u)
        v[u] = cload16((const char*)hrow32 + 512 * u + 16 * s32);
      asm volatile("s_waitcnt vmcnt(0)" ::: "memory");
      __builtin_amdgcn_sched_barrier(0);
      u32 pend = 0u;
#pragma unroll
      for (int u = 0; u < 8; ++u) {
        const u32 w0 = v[u][0], w1 = v[u][1], w2 = v[u][2], w3 = v[u][3];
        const u64 packs = (u64)((w0 & 0xffffu) | (w1 << 16)) |
                          ((u64)((w2 & 0xffffu) | (w3 << 16)) << 32);
        *(u64*)(ldsrow + ((256 * u + 8 * s32) ^ swz_w)) = packs;
        if ((w0 >> 16) < (u32)t || (w1 >> 16) < (u32)t ||
            (w2 >> 16) < (u32)t || (w3 >> 16) < (u32)t)
          pend |= (1u << u);
      }
      // rare straggler path (flag/data raced in the fabric): atomic u64 pairs
      while (__builtin_expect(pend != 0u, 0)) {
        const int uu = __ffs(pend) - 1;
        const u64* h64 = (const u64*)hrow32;
        const int j0 = 64 * uu + 2 * s32;
        u64 a = __hip_atomic_load(&h64[j0], __ATOMIC_RELAXED, __HIP_MEMORY_SCOPE_AGENT);
        u64 b = __hip_atomic_load(&h64[j0 + 1], __ATOMIC_RELAXED, __HIP_MEMORY_SCOPE_AGENT);
        const u32 t0 = (u32)(a >> 16) & 0xffffu, t1 = (u32)(a >> 48);
        const u32 t2 = (u32)(b >> 16) & 0xffffu, t3 = (u32)(b >> 48);
        if (t0 >= (u32)t && t1 >= (u32)t && t2 >= (u32)t && t3 >= (u32)t) {
          const u64 packs =
              (u64)(((u32)a & 0xffffu) | (((u32)(a >> 32) & 0xffffu) << 16)) |
              ((u64)(((u32)b & 0xffffu) | (((u32)(b >> 32) & 0xffffu) << 16)) << 32);
          *(u64*)(ldsrow + ((256 * uu + 8 * s32) ^ swz_w)) = packs;
          pend &= pend - 1u;
        }
      }
      __syncthreads();
      const char* hrd = (const char*)h_lds + rl * 2048;
#pragma unroll
      for (int kk = 0; kk < 32; kk += 2) {
        bf16x8 a0 = *(const bf16x8*)(hrd + ((kk * 64 + gq * 16) ^ swz_r));
        bf16x8 a1 = *(const bf16x8*)(hrd + (((kk + 1) * 64 + gq * 16) ^ swz_r));
        acc0 = __builtin_amdgcn_mfma_f32_16x16x32_bf16(a0, wf[kk], acc0, 0, 0, 0);
        acc1 = __builtin_amdgcn_mfma_f32_16x16x32_bf16(a1, wf[kk + 1], acc1, 0, 0, 0);
      }
      acc0 += acc1;
    } else {
      __syncthreads();
    }
    // gate exchange: wave (g,c2) tile -> C[row=gq*4+r][col=rl]
#pragma unroll
    for (int r = 0; r < 4; ++r)
      gate_lds[g][c2][gq * 4 + r][rl] = acc0[r];
    __syncthreads();
    // elementwise: thread owns (b_el, hcol)
    {
      const int cq = hcol >> 4, cl = hcol & 15;
      const float gi = gate_lds[0][cq][b_el][cl] + xg0;
      const float gf = gate_lds[1][cq][b_el][cl] + xg1;
      const float gg = gate_lds[2][cq][b_el][cl] + xg2;
      const float go = gate_lds[3][cq][b_el][cl] + xg3;
      const float iv = sigm(gi);
      const float fv = sigm(gf);
      const float gv = tanh_fast(gg);
      const float ov = sigm(go);
      creg = fv * creg + iv * gv;
      hreg = ov * tanh_fast(creg);
      // tagged h store FIRST (critical path), fire-and-forget
      const u32 wv = (u32)f2bf(hreg) | ((u32)(t + 1) << 16);
      __hip_atomic_store(
          &h_tag[(size_t)((t + 1) & 1) * 65536 + (size_t)(bg * 16 + b_el) * 1024 + cr * 32 + hcol],
          wv, __ATOMIC_RELAXED, __HIP_MEMORY_SCOPE_AGENT);
    }
    // readiness flag: immediately after h stores, no ordering ops
    if (tid == 0)
      __hip_atomic_store(&flags[bg * 32 + cr], (u32)(t + 1), __ATOMIC_RELAXED,
                         __HIP_MEMORY_SCOPE_AGENT);
    // out store after (off the critical path)
    out[((size_t)t * BATCH + bg * 16 + b_el) * HDIM + cr * 32 + hcol] = hreg;
    xg0 = bf2f(nx0); xg1 = bf2f(nx1); xg2 = bf2f(nx2); xg3 = bf2f(nx3);
    xp_p += XP_STEP;
  }
  // hT, cT
  out[(size_t)HS_ELEMS + (size_t)(bg * 16 + b_el) * HDIM + cr * 32 + hcol] = hreg;
  out[(size_t)HS_ELEMS + 65536u + (size_t)(bg * 16 + b_el) * HDIM + cr * 32 + hcol] = creg;
}

// ---------------------------------------------------------------------------
// Workspace: [0,8MB) WxT | [8,16MB) WhT | [16,272MB) Xp blocked.
// BIG mode (ws_size >= 272MB+513KB; proven available R12/R15): h_tag at
//   ws+272MB, flags = h_tag+131072; zeroed pre-gemm inside prep (no alias).
// SMALL fallback: h_tag aliases WxT, zeroed post-gemm (R9 behavior).
// d_out scratch: Xbf (64MB) at d_out base; written by prep, read by gemm,
// then overwritten by lstm_rec's out stores (stream-ordered).
// ---------------------------------------------------------------------------
extern "C" void kernel_launch(void* const* d_in, const int* in_sizes, int n_in,
                              void* d_out, int out_size, void* d_ws, size_t ws_size,
                              hipStream_t stream) {
  const float* x = (const float*)d_in[0];
  const float* Wx = (const float*)d_in[1];
  const float* Wh = (const float*)d_in[2];
  const float* bias = (const float*)d_in[3];
  float* out = (float*)d_out;
  char* ws = (char*)d_ws;

  u16* WxT = (u16*)(ws + 0);
  u16* WhT = (u16*)(ws + 8388608);
  u16* Xp = (u16*)(ws + 16777216);
  u16* Xbf = (u16*)d_out; // scratch in d_out, dead after gemm_xp

  const bool big = ws_size >= (size_t)(285212672 + 525312);
  u32* h_tag = big ? (u32*)(ws + 285212672) : (u32*)ws;
  u32* flags = h_tag + 131072;

  prep<<<dim3(25089), dim3(256), 0, stream>>>(Wx, Wh, WxT, WhT, x, Xbf, h_tag,
                                              big ? 1 : 0);
  gemm_xp<<<dim3(8192), dim3(256), 0, stream>>>(Xbf, WxT, bias, Xp);
  if (!big) zero_tags<<<dim3(513), dim3(256), 0, stream>>>(h_tag);
  lstm_rec<<<dim3(128), dim3(512), 0, stream>>>(Xp, WhT, h_tag, flags, out);
}